// Round 1
// baseline (2112.368 us; speedup 1.0000x reference)
//
#include <hip/hip_runtime.h>
#include <hip/hip_bf16.h>

// Problem constants
#define D      256
#define K      8192
#define NROWS  32768          // 16 * 2048
#define QELEMS 8388608        // NROWS * D
// d_out layout (flat float32): [0,QELEMS) quantized, [QELEMS, QELEMS+NROWS) idx-as-float, [QELEMS+NROWS] loss

// Main-kernel tiling
#define BR 64    // rows per block
#define BK 128   // codes per block-tile
#define DT 32    // d-tile
#define TM 4     // rows per thread
#define TN 8     // codes per thread
#define XSP 36   // xs tile row stride (floats): 144 B, 16B-aligned, bank-friendly
#define ESP 132  // es tile row stride (floats): 528 B, 16B-aligned, bank-friendly

// ---------------------------------------------------------------------------
// Kernel 1: se[k] = sum_d codebook[k][d]^2   (one wave per code)
__global__ void vq_se_kernel(const float* __restrict__ cb, float* __restrict__ se) {
    int k = blockIdx.x;
    int l = threadIdx.x;
    const float* row = cb + (size_t)k * D;
    float s = 0.f;
    #pragma unroll
    for (int j = 0; j < D; j += 64) { float v = row[j + l]; s += v * v; }
    #pragma unroll
    for (int off = 32; off > 0; off >>= 1) s += __shfl_down(s, off, 64);
    if (l == 0) se[k] = s;
}

// ---------------------------------------------------------------------------
// Kernel 2: fused distance + argmin.
// dist[r][k] = (sx[r] + se[k]) - 2 * dot(x[r], e[k]), fp32, matching reference.
__global__ __launch_bounds__(256) void vq_main_kernel(
    const float* __restrict__ x, const float* __restrict__ cb,
    const float* __restrict__ se, int* __restrict__ out_idx) {

    __shared__ float xs_t[BR][XSP];    // [row][d_local]
    __shared__ float es_t[DT][ESP];    // [d_local][code_local] (transposed)
    __shared__ float sxs[BR];
    __shared__ float psx[BR][4];
    __shared__ float rmins[BR][16];
    __shared__ int   ridxs[BR][16];

    const int tid = threadIdx.x;
    const int tx = tid & 15;       // code-group
    const int ty = tid >> 4;       // row-group
    const int row0 = blockIdx.x * BR;

    // ---- per-row ||x||^2 (4 partials per row, deterministic combine) ----
    {
        int r = tid >> 2, q = tid & 3;
        const float* p = x + (size_t)(row0 + r) * D + q * 64;
        float s = 0.f;
        #pragma unroll 8
        for (int j = 0; j < 64; ++j) { float v = p[j]; s += v * v; }
        psx[r][q] = s;
    }
    __syncthreads();
    if (tid < BR)
        sxs[tid] = ((psx[tid][0] + psx[tid][1]) + psx[tid][2]) + psx[tid][3];

    float rmin[TM];
    int   ridx[TM];
    #pragma unroll
    for (int r = 0; r < TM; ++r) { rmin[r] = 3.4e38f; ridx[r] = 0; }

    for (int k0 = 0; k0 < K; k0 += BK) {
        float acc[TM][TN];
        #pragma unroll
        for (int r = 0; r < TM; ++r)
            #pragma unroll
            for (int c = 0; c < TN; ++c) acc[r][c] = 0.f;

        for (int d0 = 0; d0 < D; d0 += DT) {
            __syncthreads();  // protect previous tile against overwrite
            // load x tile: BR x DT = 512 float4, 2 per thread (coalesced)
            #pragma unroll
            for (int i = 0; i < 2; ++i) {
                int f = tid + i * 256;
                int rr = f >> 3, c4 = (f & 7) * 4;
                float4 v = *(const float4*)(x + (size_t)(row0 + rr) * D + d0 + c4);
                *(float4*)&xs_t[rr][c4] = v;
            }
            // load e tile transposed: BK x DT = 1024 float4, 4 per thread
            #pragma unroll
            for (int i = 0; i < 4; ++i) {
                int f = tid + i * 256;
                int kk = f >> 3, c4 = (f & 7) * 4;
                float4 v = *(const float4*)(cb + (size_t)(k0 + kk) * D + d0 + c4);
                es_t[c4 + 0][kk] = v.x;
                es_t[c4 + 1][kk] = v.y;
                es_t[c4 + 2][kk] = v.z;
                es_t[c4 + 3][kk] = v.w;
            }
            __syncthreads();

            #pragma unroll 4
            for (int d = 0; d < DT; ++d) {
                float xv[TM];
                #pragma unroll
                for (int r = 0; r < TM; ++r) xv[r] = xs_t[ty * TM + r][d];
                float4 e0 = *(const float4*)&es_t[d][tx * TN];
                float4 e1 = *(const float4*)&es_t[d][tx * TN + 4];
                float ev[TN] = {e0.x, e0.y, e0.z, e0.w, e1.x, e1.y, e1.z, e1.w};
                #pragma unroll
                for (int r = 0; r < TM; ++r)
                    #pragma unroll
                    for (int c = 0; c < TN; ++c)
                        acc[r][c] = fmaf(xv[r], ev[c], acc[r][c]);
            }
        }

        // epilogue: distances + running argmin (k ascending -> first-index ties)
        #pragma unroll
        for (int c = 0; c < TN; ++c) {
            int k = k0 + tx * TN + c;
            float sek = se[k];
            #pragma unroll
            for (int r = 0; r < TM; ++r) {
                float dist = (sxs[ty * TM + r] + sek) - 2.0f * acc[r][c];
                if (dist < rmin[r]) { rmin[r] = dist; ridx[r] = k; }
            }
        }
    }

    __syncthreads();
    #pragma unroll
    for (int r = 0; r < TM; ++r) {
        rmins[ty * TM + r][tx] = rmin[r];
        ridxs[ty * TM + r][tx] = ridx[r];
    }
    __syncthreads();
    if (tid < BR) {
        float m = rmins[tid][0];
        int  mi = ridxs[tid][0];
        #pragma unroll
        for (int t = 1; t < 16; ++t) {
            float v = rmins[tid][t];
            int  vi = ridxs[tid][t];
            if (v < m || (v == m && vi < mi)) { m = v; mi = vi; }
        }
        out_idx[row0 + tid] = mi;
    }
}

// ---------------------------------------------------------------------------
// Kernel 3: gather quantized, write idx-as-float, accumulate sum((q-x)^2)
__global__ __launch_bounds__(256) void vq_out_kernel(
    const float* __restrict__ x, const float* __restrict__ cb,
    const int* __restrict__ idx, float* __restrict__ out,
    float* __restrict__ loss_sum) {

    int g = blockIdx.x * 256 + threadIdx.x;   // [0, NROWS*64)
    int row = g >> 6;
    int seg = (g & 63) * 4;
    int k = idx[row];

    float4 q  = *(const float4*)(cb + (size_t)k * D + seg);
    float4 xv = *(const float4*)(x + (size_t)row * D + seg);
    *(float4*)(out + (size_t)row * D + seg) = q;

    float dx0 = q.x - xv.x, dx1 = q.y - xv.y, dx2 = q.z - xv.z, dx3 = q.w - xv.w;
    float s = dx0 * dx0 + dx1 * dx1 + dx2 * dx2 + dx3 * dx3;

    __shared__ float red[256];
    red[threadIdx.x] = s;
    __syncthreads();
    #pragma unroll
    for (int off = 128; off > 0; off >>= 1) {
        if (threadIdx.x < off) red[threadIdx.x] += red[threadIdx.x + off];
        __syncthreads();
    }
    if (threadIdx.x == 0) atomicAdd(loss_sum, red[0]);
    if ((g & 63) == 0) out[QELEMS + row] = (float)k;
}

// ---------------------------------------------------------------------------
// Kernel 4: loss = (1 + 0.25) * mean((q - x)^2)
__global__ void vq_fin_kernel(const float* __restrict__ loss_sum, float* __restrict__ out) {
    out[QELEMS + NROWS] = 1.25f * (*loss_sum) * (1.0f / (float)QELEMS);
}

// ---------------------------------------------------------------------------
extern "C" void kernel_launch(void* const* d_in, const int* in_sizes, int n_in,
                              void* d_out, int out_size, void* d_ws, size_t ws_size,
                              hipStream_t stream) {
    const float* x  = (const float*)d_in[0];   // [16,2048,256] fp32
    const float* cb = (const float*)d_in[1];   // [8192,256] fp32
    float* out = (float*)d_out;

    char* ws = (char*)d_ws;
    float* loss_sum = (float*)ws;                       // 4 B
    int*   idxbuf   = (int*)(ws + 256);                 // 128 KB
    float* sebuf    = (float*)(ws + 256 + NROWS * 4);   // 32 KB

    hipMemsetAsync(loss_sum, 0, sizeof(float), stream);
    vq_se_kernel<<<K, 64, 0, stream>>>(cb, sebuf);
    vq_main_kernel<<<NROWS / BR, 256, 0, stream>>>(x, cb, sebuf, idxbuf);
    vq_out_kernel<<<(NROWS * 64) / 256, 256, 0, stream>>>(x, cb, idxbuf, out, loss_sum);
    vq_fin_kernel<<<1, 1, 0, stream>>>(loss_sum, out);
}

// Round 3
// 710.811 us; speedup vs baseline: 2.9718x; 2.9718x over previous
//
#include <hip/hip_runtime.h>
#include <hip/hip_bf16.h>
#include <stdint.h>

#define D      256
#define K      8192
#define NROWS  32768          // 16 * 2048
#define QELEMS 8388608        // NROWS * D
// d_out layout (flat f32): [0,QELEMS) quantized, [QELEMS,QELEMS+NROWS) idx, [QELEMS+NROWS] loss

typedef __attribute__((ext_vector_type(8))) short bf16x8;
typedef __attribute__((ext_vector_type(4))) float f32x4;
typedef unsigned int u32;
typedef unsigned short u16;

__device__ __forceinline__ u16 f2bf(float f) {
    u32 b = __float_as_uint(f);
    return (u16)((b + 0x7fffu + ((b >> 16) & 1u)) >> 16);   // RNE
}

// ---------------------------------------------------------------------------
__global__ __launch_bounds__(256) void cvt_kernel(const float* __restrict__ src,
                                                  u16* __restrict__ dst, int n4) {
    int i = blockIdx.x * 256 + threadIdx.x;
    if (i >= n4) return;
    float4 v = ((const float4*)src)[i];
    ushort4 o;
    o.x = f2bf(v.x); o.y = f2bf(v.y); o.z = f2bf(v.z); o.w = f2bf(v.w);
    ((ushort4*)dst)[i] = o;
}

// ---------------------------------------------------------------------------
// se[k] = sum_d codebook[k][d]^2  (IDENTICAL to round-1: rescore depends on it)
__global__ void vq_se_kernel(const float* __restrict__ cb, float* __restrict__ se) {
    int k = blockIdx.x;
    int l = threadIdx.x;
    const float* row = cb + (size_t)k * D;
    float s = 0.f;
    #pragma unroll
    for (int j = 0; j < D; j += 64) { float v = row[j + l]; s += v * v; }
    #pragma unroll
    for (int off = 32; off > 0; off >>= 1) s += __shfl_down(s, off, 64);
    if (l == 0) se[k] = s;
}

// ---------------------------------------------------------------------------
// bf16 MFMA filter (per-lane top-2, no atomics) + exact fp32 rescore.
// Codes = MFMA M dim, data-rows = N dim: each lane's acc quad shares one row.
__global__ __launch_bounds__(512, 2) void vq_mfma_kernel(
    const u16* __restrict__ xh, const u16* __restrict__ ch,
    const float* __restrict__ x, const float* __restrict__ cb,
    const float* __restrict__ se, int* __restrict__ out_idx)
{
    __shared__ u16 As[16384];          // 32 KB: 128 codes x 128 d, frag order
    __shared__ u32 cand[128][32];      // 16 KB fixed candidate slots
    __shared__ float red_sx[128][4];
    __shared__ float red_bv[128][4];
    __shared__ int   red_bk[128][4];

    const int tid  = threadIdx.x;
    const int lane = tid & 63;
    const int wave = tid >> 6;         // 0..7
    const int m_w  = wave >> 1;        // 0..3 : 32-code slice of 128-code tile
    const int n_w  = wave & 1;         // 0..1 : 64-row slice of 128-row block
    const int l15  = lane & 15;
    const int l4   = lane >> 4;        // 0..3
    const int row0 = blockIdx.x * 128;

    // x fragments (B operand) register-resident: B[k=l4*8+j][n=l15]
    bf16x8 Bf[4][8];
    #pragma unroll
    for (int nt = 0; nt < 4; ++nt) {
        const u16* xr = xh + (size_t)(row0 + n_w * 64 + nt * 16 + l15) * D + l4 * 8;
        #pragma unroll
        for (int c = 0; c < 8; ++c) Bf[nt][c] = *(const bf16x8*)(xr + c * 32);
    }

    // per-lane top-2 (value, code) per nt-row
    float b0[4], b1[4]; int c0[4], c1[4];
    #pragma unroll
    for (int nt = 0; nt < 4; ++nt) { b0[nt] = 1e30f; b1[nt] = 1e30f; c0[nt] = 0; c1[nt] = 0; }

    #pragma unroll 1
    for (int ct = 0; ct < 64; ++ct) {
        const int k0 = ct << 7;
        f32x4 acc[2][4];
        #pragma unroll
        for (int mt = 0; mt < 2; ++mt)
            #pragma unroll
            for (int nt = 0; nt < 4; ++nt) acc[mt][nt] = (f32x4){0.f, 0.f, 0.f, 0.f};

        #pragma unroll
        for (int s = 0; s < 2; ++s) {
            __syncthreads();                       // prior reads of As done
            // stage 128 codes x 128 d via registers (4 x 16B per thread)
            bf16x8 stg[4];
            #pragma unroll
            for (int i = 0; i < 4; ++i) {
                int g    = wave * 4 + i;           // 0..31
                int code = k0 + (g & 7) * 16 + l15;
                int dd   = s * 128 + (g >> 3) * 32 + l4 * 8;
                stg[i] = *(const bf16x8*)(ch + (size_t)code * D + dd);
            }
            #pragma unroll
            for (int i = 0; i < 4; ++i) {
                int g = wave * 4 + i;
                *(bf16x8*)(As + (size_t)(g * 64 + lane) * 8) = stg[i];
            }
            __syncthreads();                       // staging visible
            #pragma unroll
            for (int dc = 0; dc < 4; ++dc) {
                int c = s * 4 + dc;
                #pragma unroll
                for (int mt = 0; mt < 2; ++mt) {
                    bf16x8 Af = *(const bf16x8*)(As + (size_t)((dc * 8 + m_w * 2 + mt) * 64 + lane) * 8);
                    #pragma unroll
                    for (int nt = 0; nt < 4; ++nt)
                        acc[mt][nt] = __builtin_amdgcn_mfma_f32_16x16x32_bf16(
                            Af, Bf[nt][c], acc[mt][nt], 0, 0, 0);
                }
            }
        }

        // epilogue: t = se - 2*dot ; per-lane top-2 update
        f32x4 sev[2];
        #pragma unroll
        for (int mt = 0; mt < 2; ++mt)
            sev[mt] = *(const f32x4*)(se + k0 + (m_w * 2 + mt) * 16 + l4 * 4);

        #pragma unroll
        for (int nt = 0; nt < 4; ++nt) {
            float tv[8];
            #pragma unroll
            for (int mt = 0; mt < 2; ++mt)
                #pragma unroll
                for (int r = 0; r < 4; ++r)
                    tv[mt * 4 + r] = fmaf(-2.f, acc[mt][nt][r], sev[mt][r]);
            float tmn = tv[0];
            #pragma unroll
            for (int j = 1; j < 8; ++j) tmn = fminf(tmn, tv[j]);
            if (tmn < b1[nt]) {                    // rare after first tiles
                #pragma unroll
                for (int mt = 0; mt < 2; ++mt)
                    #pragma unroll
                    for (int r = 0; r < 4; ++r) {
                        float t = tv[mt * 4 + r];
                        int  cv = k0 + (m_w * 2 + mt) * 16 + l4 * 4 + r;
                        bool in0 = t < b0[nt];
                        bool in1 = t < b1[nt];
                        float ob0 = b0[nt]; int oc0 = c0[nt];
                        b1[nt] = in0 ? ob0 : (in1 ? t  : b1[nt]);
                        c1[nt] = in0 ? oc0 : (in1 ? cv : c1[nt]);
                        b0[nt] = in0 ? t  : ob0;
                        c0[nt] = in0 ? cv : oc0;
                    }
            }
        }
    }

    // ---- fixed-slot handoff (no atomics) ----
    __syncthreads();
    #pragma unroll
    for (int nt = 0; nt < 4; ++nt) {
        int rl = n_w * 64 + nt * 16 + l15;
        int sl = (m_w * 4 + l4) * 2;
        cand[rl][sl]     = (u32)c0[nt];
        cand[rl][sl + 1] = (u32)c1[nt];
    }

    // ---- exact fp32 rescore of all 32 slots (round-1 arithmetic) ----
    const int rr = tid >> 2;       // 0..127
    const int cq = tid & 3;
    const int grow = row0 + rr;
    {
        const float* p = x + (size_t)grow * D + cq * 64;
        float sp = 0.f;
        #pragma unroll 8
        for (int j = 0; j < 64; ++j) { float v = p[j]; sp += v * v; }
        red_sx[rr][cq] = sp;
    }
    __syncthreads();   // cand + red_sx visible
    float sx = ((red_sx[rr][0] + red_sx[rr][1]) + red_sx[rr][2]) + red_sx[rr][3];

    float best = 1e30f; int bk = 0x7fffffff;
    const float* xr = x + (size_t)grow * D;
    for (int j = cq; j < 32; j += 4) {
        int code = (int)cand[rr][j];
        const float* er = cb + (size_t)code * D;
        float a = 0.f;
        #pragma unroll 8
        for (int d2 = 0; d2 < D; ++d2) a = fmaf(xr[d2], er[d2], a);
        float dist = (sx + se[code]) - 2.0f * a;
        if (dist < best || (dist == best && code < bk)) { best = dist; bk = code; }
    }
    red_bv[rr][cq] = best; red_bk[rr][cq] = bk;
    __syncthreads();
    if (cq == 0) {
        float bv = red_bv[rr][0]; int b = red_bk[rr][0];
        #pragma unroll
        for (int t2 = 1; t2 < 4; ++t2) {
            float v = red_bv[rr][t2]; int k2 = red_bk[rr][t2];
            if (v < bv || (v == bv && k2 < b)) { bv = v; b = k2; }
        }
        out_idx[grow] = b;
    }
}

// ---------------------------------------------------------------------------
// Gather quantized, write idx-as-float, accumulate sum((q-x)^2)
__global__ __launch_bounds__(256) void vq_out_kernel(
    const float* __restrict__ x, const float* __restrict__ cb,
    const int* __restrict__ idx, float* __restrict__ out,
    float* __restrict__ loss_sum) {

    int g = blockIdx.x * 256 + threadIdx.x;   // [0, NROWS*64)
    int row = g >> 6;
    int seg = (g & 63) * 4;
    int k = idx[row];

    float4 q  = *(const float4*)(cb + (size_t)k * D + seg);
    float4 xv = *(const float4*)(x + (size_t)row * D + seg);
    *(float4*)(out + (size_t)row * D + seg) = q;

    float dx0 = q.x - xv.x, dx1 = q.y - xv.y, dx2 = q.z - xv.z, dx3 = q.w - xv.w;
    float s = dx0 * dx0 + dx1 * dx1 + dx2 * dx2 + dx3 * dx3;

    __shared__ float red[256];
    red[threadIdx.x] = s;
    __syncthreads();
    #pragma unroll
    for (int off = 128; off > 0; off >>= 1) {
        if (threadIdx.x < off) red[threadIdx.x] += red[threadIdx.x + off];
        __syncthreads();
    }
    if (threadIdx.x == 0) atomicAdd(loss_sum, red[0]);
    if ((g & 63) == 0) out[QELEMS + row] = (float)k;
}

// ---------------------------------------------------------------------------
__global__ void vq_fin_kernel(const float* __restrict__ loss_sum, float* __restrict__ out) {
    out[QELEMS + NROWS] = 1.25f * (*loss_sum) * (1.0f / (float)QELEMS);
}

// ---------------------------------------------------------------------------
extern "C" void kernel_launch(void* const* d_in, const int* in_sizes, int n_in,
                              void* d_out, int out_size, void* d_ws, size_t ws_size,
                              hipStream_t stream) {
    const float* x  = (const float*)d_in[0];   // [16,2048,256] fp32
    const float* cb = (const float*)d_in[1];   // [8192,256] fp32
    float* out = (float*)d_out;

    // bf16 scratch in d_out bytes [0, 20.97M) — consumed before vq_out writes.
    u16* xh = (u16*)d_out;                     // 16.78 MB
    u16* ch = xh + QELEMS;                     // 4.19 MB

    char* ws = (char*)d_ws;
    float* loss_sum = (float*)ws;                       // 4 B
    int*   idxbuf   = (int*)(ws + 256);                 // 128 KB
    float* sebuf    = (float*)(ws + 256 + NROWS * 4);   // 32 KB

    hipMemsetAsync(loss_sum, 0, sizeof(float), stream);
    cvt_kernel<<<QELEMS / 4 / 256, 256, 0, stream>>>(x, xh, QELEMS / 4);
    cvt_kernel<<<(K * D / 4) / 256, 256, 0, stream>>>(cb, ch, K * D / 4);
    vq_se_kernel<<<K, 64, 0, stream>>>(cb, sebuf);
    vq_mfma_kernel<<<NROWS / 128, 512, 0, stream>>>(xh, ch, x, cb, sebuf, idxbuf);
    vq_out_kernel<<<(NROWS * 64) / 256, 256, 0, stream>>>(x, cb, idxbuf, out, loss_sum);
    vq_fin_kernel<<<1, 1, 0, stream>>>(loss_sum, out);
}

// Round 4
// 593.911 us; speedup vs baseline: 3.5567x; 1.1968x over previous
//
#include <hip/hip_runtime.h>
#include <hip/hip_bf16.h>
#include <stdint.h>

#define D      256
#define K      8192
#define NROWS  32768          // 16 * 2048
#define QELEMS 8388608        // NROWS * D
// d_out layout (flat f32): [0,QELEMS) quantized, [QELEMS,QELEMS+NROWS) idx, [QELEMS+NROWS] loss

typedef __attribute__((ext_vector_type(8))) short bf16x8;
typedef __attribute__((ext_vector_type(4))) float f32x4;
typedef unsigned int u32;
typedef unsigned short u16;

__device__ __forceinline__ u16 f2bf(float f) {
    u32 b = __float_as_uint(f);
    return (u16)((b + 0x7fffu + ((b >> 16) & 1u)) >> 16);   // RNE
}

// ---------------------------------------------------------------------------
// Prep: cb fp32 -> ch bf16, se[k] = ||cb[k]||^2, zero loss accumulator.
// One wave per codebook row.
__global__ __launch_bounds__(256) void vq_prep_kernel(
    const float* __restrict__ cb, u16* __restrict__ ch,
    float* __restrict__ se, float* __restrict__ loss_sum) {
    int row = blockIdx.x * 4 + (threadIdx.x >> 6);
    int l = threadIdx.x & 63;
    float4 v = *(const float4*)(cb + (size_t)row * D + l * 4);
    ushort4 o;
    o.x = f2bf(v.x); o.y = f2bf(v.y); o.z = f2bf(v.z); o.w = f2bf(v.w);
    *(ushort4*)(ch + (size_t)row * D + l * 4) = o;
    float s = v.x * v.x + v.y * v.y + v.z * v.z + v.w * v.w;
    #pragma unroll
    for (int off = 32; off > 0; off >>= 1) s += __shfl_down(s, off, 64);
    if (l == 0) se[row] = s;
    if (blockIdx.x == 0 && threadIdx.x == 0) *loss_sum = 0.f;
}

// ---------------------------------------------------------------------------
// Main: barrier-free bf16 MFMA filter (A-frags direct from global, x-frags
// register-resident) + per-lane top-2 + exact fp32 rescore (R3-verified).
// Codes = MFMA M dim, data-rows = N dim.
__global__ __launch_bounds__(512, 2) void vq_mfma_kernel(
    const u16* __restrict__ ch, const float* __restrict__ x,
    const float* __restrict__ cb, const float* __restrict__ se,
    int* __restrict__ out_idx, float* __restrict__ out_f)
{
    __shared__ u32 cand[128][32];      // 16 KB fixed candidate slots
    __shared__ float red_sx[128][4];
    __shared__ float red_bv[128][4];
    __shared__ int   red_bk[128][4];

    const int tid  = threadIdx.x;
    const int lane = tid & 63;
    const int wave = tid >> 6;         // 0..7
    const int m_w  = wave >> 1;        // 0..3 : 32-code slice of 128-code tile
    const int n_w  = wave & 1;         // 0..1 : 64-row slice of 128-row block
    const int l15  = lane & 15;
    const int l4   = lane >> 4;        // 0..3
    const int row0 = blockIdx.x * 128;

    // x fragments (B operand) register-resident, converted in-register.
    // B[k=l4*8+j][n=l15]; same f2bf rounding as the bf16 codebook path.
    bf16x8 Bf[4][8];
    #pragma unroll
    for (int nt = 0; nt < 4; ++nt) {
        const float* xr = x + (size_t)(row0 + n_w * 64 + nt * 16 + l15) * D + l4 * 8;
        #pragma unroll
        for (int c = 0; c < 8; ++c) {
            float4 a = *(const float4*)(xr + c * 32);
            float4 b = *(const float4*)(xr + c * 32 + 4);
            bf16x8 f;
            f[0] = (short)f2bf(a.x); f[1] = (short)f2bf(a.y);
            f[2] = (short)f2bf(a.z); f[3] = (short)f2bf(a.w);
            f[4] = (short)f2bf(b.x); f[5] = (short)f2bf(b.y);
            f[6] = (short)f2bf(b.z); f[7] = (short)f2bf(b.w);
            Bf[nt][c] = f;
        }
    }

    // per-lane top-2 (value, code) per nt-row
    float b0[4], b1[4]; int c0[4], c1[4];
    #pragma unroll
    for (int nt = 0; nt < 4; ++nt) { b0[nt] = 1e30f; b1[nt] = 1e30f; c0[nt] = 0; c1[nt] = 0; }

    const u16* ap0 = ch + (size_t)((m_w * 2 + 0) * 16 + l15) * D + l4 * 8;
    const u16* ap1 = ch + (size_t)((m_w * 2 + 1) * 16 + l15) * D + l4 * 8;

    #pragma unroll 1
    for (int ct = 0; ct < 64; ++ct) {
        const int k0 = ct << 7;
        // A fragments: 16 direct 16B loads from L2-resident bf16 codebook.
        bf16x8 Af[2][8];
        {
            const u16* a0 = ap0 + (size_t)k0 * D;
            const u16* a1 = ap1 + (size_t)k0 * D;
            #pragma unroll
            for (int c = 0; c < 8; ++c) {
                Af[0][c] = *(const bf16x8*)(a0 + c * 32);
                Af[1][c] = *(const bf16x8*)(a1 + c * 32);
            }
        }

        f32x4 acc[2][4];
        #pragma unroll
        for (int mt = 0; mt < 2; ++mt)
            #pragma unroll
            for (int nt = 0; nt < 4; ++nt) acc[mt][nt] = (f32x4){0.f, 0.f, 0.f, 0.f};

        #pragma unroll
        for (int c = 0; c < 8; ++c)
            #pragma unroll
            for (int mt = 0; mt < 2; ++mt)
                #pragma unroll
                for (int nt = 0; nt < 4; ++nt)
                    acc[mt][nt] = __builtin_amdgcn_mfma_f32_16x16x32_bf16(
                        Af[mt][c], Bf[nt][c], acc[mt][nt], 0, 0, 0);

        // epilogue: t = se - 2*dot ; per-lane top-2 update (R3-identical)
        f32x4 sev[2];
        #pragma unroll
        for (int mt = 0; mt < 2; ++mt)
            sev[mt] = *(const f32x4*)(se + k0 + (m_w * 2 + mt) * 16 + l4 * 4);

        #pragma unroll
        for (int nt = 0; nt < 4; ++nt) {
            float tv[8];
            #pragma unroll
            for (int mt = 0; mt < 2; ++mt)
                #pragma unroll
                for (int r = 0; r < 4; ++r)
                    tv[mt * 4 + r] = fmaf(-2.f, acc[mt][nt][r], sev[mt][r]);
            float tmn = tv[0];
            #pragma unroll
            for (int j = 1; j < 8; ++j) tmn = fminf(tmn, tv[j]);
            if (tmn < b1[nt]) {                    // rare after first tiles
                #pragma unroll
                for (int mt = 0; mt < 2; ++mt)
                    #pragma unroll
                    for (int r = 0; r < 4; ++r) {
                        float t = tv[mt * 4 + r];
                        int  cv = k0 + (m_w * 2 + mt) * 16 + l4 * 4 + r;
                        bool in0 = t < b0[nt];
                        bool in1 = t < b1[nt];
                        float ob0 = b0[nt]; int oc0 = c0[nt];
                        b1[nt] = in0 ? ob0 : (in1 ? t  : b1[nt]);
                        c1[nt] = in0 ? oc0 : (in1 ? cv : c1[nt]);
                        b0[nt] = in0 ? t  : ob0;
                        c0[nt] = in0 ? cv : oc0;
                    }
            }
        }
    }

    // ---- fixed-slot handoff (no atomics) ----
    #pragma unroll
    for (int nt = 0; nt < 4; ++nt) {
        int rl = n_w * 64 + nt * 16 + l15;
        int sl = (m_w * 4 + l4) * 2;
        cand[rl][sl]     = (u32)c0[nt];
        cand[rl][sl + 1] = (u32)c1[nt];
    }

    // ---- exact fp32 rescore of all 32 slots (round-1 arithmetic) ----
    const int rr = tid >> 2;       // 0..127
    const int cq = tid & 3;
    const int grow = row0 + rr;
    {
        const float* p = x + (size_t)grow * D + cq * 64;
        float sp = 0.f;
        #pragma unroll 8
        for (int j = 0; j < 64; ++j) { float v = p[j]; sp += v * v; }
        red_sx[rr][cq] = sp;
    }
    __syncthreads();   // cand + red_sx visible
    float sx = ((red_sx[rr][0] + red_sx[rr][1]) + red_sx[rr][2]) + red_sx[rr][3];

    float best = 1e30f; int bk = 0x7fffffff;
    const float* xr = x + (size_t)grow * D;
    for (int j = cq; j < 32; j += 4) {
        int code = (int)cand[rr][j];
        const float* er = cb + (size_t)code * D;
        float a = 0.f;
        #pragma unroll 8
        for (int d2 = 0; d2 < D; ++d2) a = fmaf(xr[d2], er[d2], a);
        float dist = (sx + se[code]) - 2.0f * a;
        if (dist < best || (dist == best && code < bk)) { best = dist; bk = code; }
    }
    red_bv[rr][cq] = best; red_bk[rr][cq] = bk;
    __syncthreads();
    if (cq == 0) {
        float bv = red_bv[rr][0]; int b = red_bk[rr][0];
        #pragma unroll
        for (int t2 = 1; t2 < 4; ++t2) {
            float v = red_bv[rr][t2]; int k2 = red_bk[rr][t2];
            if (v < bv || (v == bv && k2 < b)) { bv = v; b = k2; }
        }
        out_idx[grow] = b;
        out_f[QELEMS + grow] = (float)b;   // idx-as-float (disjoint from ch region)
    }
}

// ---------------------------------------------------------------------------
// Gather quantized + loss partial. 2048 blocks, 16 rows each, ONE atomic/block.
__global__ __launch_bounds__(256) void vq_out_kernel(
    const float* __restrict__ x, const float* __restrict__ cb,
    const int* __restrict__ idx, float* __restrict__ out,
    float* __restrict__ loss_sum) {

    float s = 0.f;
    #pragma unroll
    for (int i = 0; i < 4; ++i) {
        int g = blockIdx.x * 1024 + i * 256 + threadIdx.x;
        int row = g >> 6;
        int seg = (g & 63) * 4;
        int k = idx[row];
        float4 q  = *(const float4*)(cb + (size_t)k * D + seg);
        float4 xv = *(const float4*)(x + (size_t)row * D + seg);
        *(float4*)(out + (size_t)row * D + seg) = q;
        float dx0 = q.x - xv.x, dx1 = q.y - xv.y, dx2 = q.z - xv.z, dx3 = q.w - xv.w;
        s += dx0 * dx0 + dx1 * dx1 + dx2 * dx2 + dx3 * dx3;
    }

    __shared__ float red[256];
    red[threadIdx.x] = s;
    __syncthreads();
    #pragma unroll
    for (int off = 128; off > 0; off >>= 1) {
        if (threadIdx.x < off) red[threadIdx.x] += red[threadIdx.x + off];
        __syncthreads();
    }
    if (threadIdx.x == 0) atomicAdd(loss_sum, red[0]);
}

// ---------------------------------------------------------------------------
__global__ void vq_fin_kernel(const float* __restrict__ loss_sum, float* __restrict__ out) {
    out[QELEMS + NROWS] = 1.25f * (*loss_sum) * (1.0f / (float)QELEMS);
}

// ---------------------------------------------------------------------------
extern "C" void kernel_launch(void* const* d_in, const int* in_sizes, int n_in,
                              void* d_out, int out_size, void* d_ws, size_t ws_size,
                              hipStream_t stream) {
    const float* x  = (const float*)d_in[0];   // [16,2048,256] fp32
    const float* cb = (const float*)d_in[1];   // [8192,256] fp32
    float* out = (float*)d_out;

    // bf16 codebook scratch in d_out bytes [0, 4.19M) — consumed by vq_mfma
    // before vq_out overwrites the quantized region.
    u16* ch = (u16*)d_out;

    char* ws = (char*)d_ws;
    float* loss_sum = (float*)ws;                       // 4 B
    int*   idxbuf   = (int*)(ws + 256);                 // 128 KB
    float* sebuf    = (float*)(ws + 256 + NROWS * 4);   // 32 KB

    vq_prep_kernel<<<K / 4, 256, 0, stream>>>(cb, ch, sebuf, loss_sum);
    vq_mfma_kernel<<<NROWS / 128, 512, 0, stream>>>(ch, x, cb, sebuf, idxbuf, out);
    vq_out_kernel<<<NROWS / 16, 256, 0, stream>>>(x, cb, idxbuf, out, loss_sum);
    vq_fin_kernel<<<1, 1, 0, stream>>>(loss_sum, out);
}

// Round 5
// 592.020 us; speedup vs baseline: 3.5681x; 1.0032x over previous
//
#include <hip/hip_runtime.h>
#include <hip/hip_bf16.h>
#include <stdint.h>

#define D      256
#define K      8192
#define NROWS  32768          // 16 * 2048
#define QELEMS 8388608        // NROWS * D
// d_out layout (flat f32): [0,QELEMS) quantized, [QELEMS,QELEMS+NROWS) idx, [QELEMS+NROWS] loss

typedef __attribute__((ext_vector_type(8))) short bf16x8;
typedef __attribute__((ext_vector_type(4))) float f32x4;
typedef unsigned int u32;
typedef unsigned short u16;

__device__ __forceinline__ u16 f2bf(float f) {
    u32 b = __float_as_uint(f);
    return (u16)((b + 0x7fffu + ((b >> 16) & 1u)) >> 16);   // RNE
}

// ---------------------------------------------------------------------------
// Prep: cb fp32 -> ch bf16, se[k] = ||cb[k]||^2, zero loss accumulator.
__global__ __launch_bounds__(256) void vq_prep_kernel(
    const float* __restrict__ cb, u16* __restrict__ ch,
    float* __restrict__ se, float* __restrict__ loss_sum) {
    int row = blockIdx.x * 4 + (threadIdx.x >> 6);
    int l = threadIdx.x & 63;
    float4 v = *(const float4*)(cb + (size_t)row * D + l * 4);
    ushort4 o;
    o.x = f2bf(v.x); o.y = f2bf(v.y); o.z = f2bf(v.z); o.w = f2bf(v.w);
    *(ushort4*)(ch + (size_t)row * D + l * 4) = o;
    float s = v.x * v.x + v.y * v.y + v.z * v.z + v.w * v.w;
    #pragma unroll
    for (int off = 32; off > 0; off >>= 1) s += __shfl_down(s, off, 64);
    if (l == 0) se[row] = s;
    if (blockIdx.x == 0 && threadIdx.x == 0) *loss_sum = 0.f;
}

// ---------------------------------------------------------------------------
// Main: barrier-free bf16 MFMA filter + per-lane top-2 + exact fp32 rescore.
// Codes = MFMA M dim, data-rows = N dim. Grid = 256 blocks = 1 block/CU, so
// occupancy is grid-capped at 2 waves/SIMD: VGPR<=256 is free. Force the
// allocator there (waves_per_eu(2,2)) so Bf[4][8] (128 VGPRs) stays resident
// — R3/R4 spilled it to scratch (WRITE_SIZE 22 MB) and ran latency-bound.
__global__ __attribute__((amdgpu_waves_per_eu(2, 2)))
__launch_bounds__(512) void vq_mfma_kernel(
    const u16* __restrict__ ch, const float* __restrict__ x,
    const float* __restrict__ cb, const float* __restrict__ se,
    int* __restrict__ out_idx, float* __restrict__ out_f)
{
    __shared__ u32 cand[128][32];      // 16 KB fixed candidate slots
    __shared__ float red_sx[128][4];
    __shared__ float red_bv[128][4];
    __shared__ int   red_bk[128][4];

    const int tid  = threadIdx.x;
    const int lane = tid & 63;
    const int wave = tid >> 6;         // 0..7
    const int m_w  = wave >> 1;        // 0..3 : 32-code slice of 128-code tile
    const int n_w  = wave & 1;         // 0..1 : 64-row slice of 128-row block
    const int l15  = lane & 15;
    const int l4   = lane >> 4;        // 0..3
    const int row0 = blockIdx.x * 128;

    // x fragments (B operand) register-resident, converted in-register.
    // B[k=l4*8+j][n=l15]; same f2bf rounding as the bf16 codebook path.
    bf16x8 Bf[4][8];
    #pragma unroll
    for (int nt = 0; nt < 4; ++nt) {
        const float* xr = x + (size_t)(row0 + n_w * 64 + nt * 16 + l15) * D + l4 * 8;
        #pragma unroll
        for (int c = 0; c < 8; ++c) {
            float4 a = *(const float4*)(xr + c * 32);
            float4 b = *(const float4*)(xr + c * 32 + 4);
            bf16x8 f;
            f[0] = (short)f2bf(a.x); f[1] = (short)f2bf(a.y);
            f[2] = (short)f2bf(a.z); f[3] = (short)f2bf(a.w);
            f[4] = (short)f2bf(b.x); f[5] = (short)f2bf(b.y);
            f[6] = (short)f2bf(b.z); f[7] = (short)f2bf(b.w);
            Bf[nt][c] = f;
        }
    }

    // per-lane top-2 (value, code) per nt-row
    float b0[4], b1[4]; int c0[4], c1[4];
    #pragma unroll
    for (int nt = 0; nt < 4; ++nt) { b0[nt] = 1e30f; b1[nt] = 1e30f; c0[nt] = 0; c1[nt] = 0; }

    const u16* ap0 = ch + (size_t)((m_w * 2 + 0) * 16 + l15) * D + l4 * 8;
    const u16* ap1 = ch + (size_t)((m_w * 2 + 1) * 16 + l15) * D + l4 * 8;

    #pragma unroll 1
    for (int ct = 0; ct < 64; ++ct) {
        const int k0 = ct << 7;
        // A fragments: 16 direct 16B loads from L2-resident bf16 codebook.
        bf16x8 Af[2][8];
        {
            const u16* a0 = ap0 + (size_t)k0 * D;
            const u16* a1 = ap1 + (size_t)k0 * D;
            #pragma unroll
            for (int c = 0; c < 8; ++c) {
                Af[0][c] = *(const bf16x8*)(a0 + c * 32);
                Af[1][c] = *(const bf16x8*)(a1 + c * 32);
            }
        }

        f32x4 acc[2][4];
        #pragma unroll
        for (int mt = 0; mt < 2; ++mt)
            #pragma unroll
            for (int nt = 0; nt < 4; ++nt) acc[mt][nt] = (f32x4){0.f, 0.f, 0.f, 0.f};

        #pragma unroll
        for (int c = 0; c < 8; ++c)
            #pragma unroll
            for (int mt = 0; mt < 2; ++mt)
                #pragma unroll
                for (int nt = 0; nt < 4; ++nt)
                    acc[mt][nt] = __builtin_amdgcn_mfma_f32_16x16x32_bf16(
                        Af[mt][c], Bf[nt][c], acc[mt][nt], 0, 0, 0);

        // epilogue: t = se - 2*dot ; per-lane top-2 (recompute t in rare path
        // from still-live acc: same values/order as R3/R4, fewer live regs)
        f32x4 sev[2];
        #pragma unroll
        for (int mt = 0; mt < 2; ++mt)
            sev[mt] = *(const f32x4*)(se + k0 + (m_w * 2 + mt) * 16 + l4 * 4);

        #pragma unroll
        for (int nt = 0; nt < 4; ++nt) {
            float tmn = 1e30f;
            #pragma unroll
            for (int mt = 0; mt < 2; ++mt)
                #pragma unroll
                for (int r = 0; r < 4; ++r)
                    tmn = fminf(tmn, fmaf(-2.f, acc[mt][nt][r], sev[mt][r]));
            if (tmn < b1[nt]) {                    // rare after first tiles
                #pragma unroll
                for (int mt = 0; mt < 2; ++mt)
                    #pragma unroll
                    for (int r = 0; r < 4; ++r) {
                        float t = fmaf(-2.f, acc[mt][nt][r], sev[mt][r]);
                        int  cv = k0 + (m_w * 2 + mt) * 16 + l4 * 4 + r;
                        bool in0 = t < b0[nt];
                        bool in1 = t < b1[nt];
                        float ob0 = b0[nt]; int oc0 = c0[nt];
                        b1[nt] = in0 ? ob0 : (in1 ? t  : b1[nt]);
                        c1[nt] = in0 ? oc0 : (in1 ? cv : c1[nt]);
                        b0[nt] = in0 ? t  : ob0;
                        c0[nt] = in0 ? cv : oc0;
                    }
            }
        }
    }

    // ---- fixed-slot handoff (no atomics) ----
    #pragma unroll
    for (int nt = 0; nt < 4; ++nt) {
        int rl = n_w * 64 + nt * 16 + l15;
        int sl = (m_w * 4 + l4) * 2;
        cand[rl][sl]     = (u32)c0[nt];
        cand[rl][sl + 1] = (u32)c1[nt];
    }

    // ---- exact fp32 rescore of all 32 slots (round-1 arithmetic) ----
    const int rr = tid >> 2;       // 0..127
    const int cq = tid & 3;
    const int grow = row0 + rr;
    {
        const float* p = x + (size_t)grow * D + cq * 64;
        float sp = 0.f;
        #pragma unroll 8
        for (int j = 0; j < 64; ++j) { float v = p[j]; sp += v * v; }
        red_sx[rr][cq] = sp;
    }
    __syncthreads();   // cand + red_sx visible
    float sx = ((red_sx[rr][0] + red_sx[rr][1]) + red_sx[rr][2]) + red_sx[rr][3];

    float best = 1e30f; int bk = 0x7fffffff;
    const float* xr = x + (size_t)grow * D;
    for (int j = cq; j < 32; j += 4) {
        int code = (int)cand[rr][j];
        const float* er = cb + (size_t)code * D;
        float a = 0.f;
        #pragma unroll 8
        for (int d2 = 0; d2 < D; ++d2) a = fmaf(xr[d2], er[d2], a);
        float dist = (sx + se[code]) - 2.0f * a;
        if (dist < best || (dist == best && code < bk)) { best = dist; bk = code; }
    }
    red_bv[rr][cq] = best; red_bk[rr][cq] = bk;
    __syncthreads();
    if (cq == 0) {
        float bv = red_bv[rr][0]; int b = red_bk[rr][0];
        #pragma unroll
        for (int t2 = 1; t2 < 4; ++t2) {
            float v = red_bv[rr][t2]; int k2 = red_bk[rr][t2];
            if (v < bv || (v == bv && k2 < b)) { bv = v; b = k2; }
        }
        out_idx[grow] = b;
        out_f[QELEMS + grow] = (float)b;   // idx-as-float (disjoint from ch region)
    }
}

// ---------------------------------------------------------------------------
// Gather quantized + loss partial. 2048 blocks, 16 rows each, ONE atomic/block.
__global__ __launch_bounds__(256) void vq_out_kernel(
    const float* __restrict__ x, const float* __restrict__ cb,
    const int* __restrict__ idx, float* __restrict__ out,
    float* __restrict__ loss_sum) {

    float s = 0.f;
    #pragma unroll
    for (int i = 0; i < 4; ++i) {
        int g = blockIdx.x * 1024 + i * 256 + threadIdx.x;
        int row = g >> 6;
        int seg = (g & 63) * 4;
        int k = idx[row];
        float4 q  = *(const float4*)(cb + (size_t)k * D + seg);
        float4 xv = *(const float4*)(x + (size_t)row * D + seg);
        *(float4*)(out + (size_t)row * D + seg) = q;
        float dx0 = q.x - xv.x, dx1 = q.y - xv.y, dx2 = q.z - xv.z, dx3 = q.w - xv.w;
        s += dx0 * dx0 + dx1 * dx1 + dx2 * dx2 + dx3 * dx3;
    }

    __shared__ float red[256];
    red[threadIdx.x] = s;
    __syncthreads();
    #pragma unroll
    for (int off = 128; off > 0; off >>= 1) {
        if (threadIdx.x < off) red[threadIdx.x] += red[threadIdx.x + off];
        __syncthreads();
    }
    if (threadIdx.x == 0) atomicAdd(loss_sum, red[0]);
}

// ---------------------------------------------------------------------------
__global__ void vq_fin_kernel(const float* __restrict__ loss_sum, float* __restrict__ out) {
    out[QELEMS + NROWS] = 1.25f * (*loss_sum) * (1.0f / (float)QELEMS);
}

// ---------------------------------------------------------------------------
extern "C" void kernel_launch(void* const* d_in, const int* in_sizes, int n_in,
                              void* d_out, int out_size, void* d_ws, size_t ws_size,
                              hipStream_t stream) {
    const float* x  = (const float*)d_in[0];   // [16,2048,256] fp32
    const float* cb = (const float*)d_in[1];   // [8192,256] fp32
    float* out = (float*)d_out;

    // bf16 codebook scratch in d_out bytes [0, 4.19M) — consumed by vq_mfma
    // before vq_out overwrites the quantized region.
    u16* ch = (u16*)d_out;

    char* ws = (char*)d_ws;
    float* loss_sum = (float*)ws;                       // 4 B
    int*   idxbuf   = (int*)(ws + 256);                 // 128 KB
    float* sebuf    = (float*)(ws + 256 + NROWS * 4);   // 32 KB

    vq_prep_kernel<<<K / 4, 256, 0, stream>>>(cb, ch, sebuf, loss_sum);
    vq_mfma_kernel<<<NROWS / 128, 512, 0, stream>>>(ch, x, cb, sebuf, idxbuf, out);
    vq_out_kernel<<<NROWS / 16, 256, 0, stream>>>(x, cb, idxbuf, out, loss_sum);
    vq_fin_kernel<<<1, 1, 0, stream>>>(loss_sum, out);
}

// Round 6
// 571.439 us; speedup vs baseline: 3.6966x; 1.0360x over previous
//
#include <hip/hip_runtime.h>
#include <hip/hip_bf16.h>
#include <stdint.h>

#define D      256
#define K      8192
#define NROWS  32768          // 16 * 2048
#define QELEMS 8388608        // NROWS * D
// d_out layout (flat f32): [0,QELEMS) quantized, [QELEMS,QELEMS+NROWS) idx, [QELEMS+NROWS] loss

typedef __attribute__((ext_vector_type(8))) short bf16x8;
typedef __attribute__((ext_vector_type(4))) float f32x4;
typedef unsigned int u32;
typedef unsigned short u16;

__device__ __forceinline__ u16 f2bf(float f) {
    u32 b = __float_as_uint(f);
    return (u16)((b + 0x7fffu + ((b >> 16) & 1u)) >> 16);   // RNE
}

// ---------------------------------------------------------------------------
// Prep: cb fp32 -> ch bf16, se[k] = ||cb[k]||^2, zero loss accumulator.
__global__ __launch_bounds__(256) void vq_prep_kernel(
    const float* __restrict__ cb, u16* __restrict__ ch,
    float* __restrict__ se, float* __restrict__ loss_sum) {
    int row = blockIdx.x * 4 + (threadIdx.x >> 6);
    int l = threadIdx.x & 63;
    float4 v = *(const float4*)(cb + (size_t)row * D + l * 4);
    ushort4 o;
    o.x = f2bf(v.x); o.y = f2bf(v.y); o.z = f2bf(v.z); o.w = f2bf(v.w);
    *(ushort4*)(ch + (size_t)row * D + l * 4) = o;
    float s = v.x * v.x + v.y * v.y + v.z * v.z + v.w * v.w;
    #pragma unroll
    for (int off = 32; off > 0; off >>= 1) s += __shfl_down(s, off, 64);
    if (l == 0) se[row] = s;
    if (blockIdx.x == 0 && threadIdx.x == 0) *loss_sum = 0.f;
}

// ---------------------------------------------------------------------------
// Main: bf16 MFMA filter with x-fragments staged in LDS (frag order, one-time)
// + per-lane top-2 + exact fp32 rescore (R3-verified arithmetic, bit-identical).
// Codes = MFMA M dim, data-rows = N dim. Low register pressure by design:
// only A-frags (64 VGPRs) + acc (AGPR-eligible) live in registers.
__global__ __attribute__((amdgpu_waves_per_eu(2, 2)))
__launch_bounds__(512) void vq_mfma_kernel(
    const u16* __restrict__ ch, const float* __restrict__ x,
    const float* __restrict__ cb, const float* __restrict__ se,
    int* __restrict__ out_idx, float* __restrict__ out_f)
{
    __shared__ u16 xf[32768];          // 64 KB: 128 rows x 256 d bf16, frag order
    __shared__ u32 cand[128][32];      // 16 KB fixed candidate slots
    __shared__ float red_sx[128][4];
    __shared__ float red_bv[128][4];
    __shared__ int   red_bk[128][4];

    const int tid  = threadIdx.x;
    const int lane = tid & 63;
    const int wave = tid >> 6;         // 0..7
    const int m_w  = wave >> 1;        // 0..3 : 32-code slice of 128-code tile
    const int n_w  = wave & 1;         // 0..1 : 64-row slice of 128-row block
    const int l15  = lane & 15;
    const int l4   = lane >> 4;        // 0..3
    const int row0 = blockIdx.x * 128;

    // ---- one-time stage: x (fp32, global) -> xf (bf16, LDS) in frag order ----
    // entry e in [0,4096) of 16 B: chunk q=e>>6 (= g2*8+c), lane le=e&63;
    // holds x[row0 + (q>>3)*16 + (le&15)][(q&7)*32 + (le>>4)*8 + j], j=0..7.
    #pragma unroll
    for (int i = 0; i < 8; ++i) {
        int e  = tid + i * 512;
        int q  = e >> 6, le = e & 63;
        int rl = (q >> 3) * 16 + (le & 15);
        int kk = (q & 7) * 32 + (le >> 4) * 8;
        const float* xp = x + (size_t)(row0 + rl) * D + kk;
        float4 a = *(const float4*)xp;
        float4 b = *(const float4*)(xp + 4);
        bf16x8 f;
        f[0] = (short)f2bf(a.x); f[1] = (short)f2bf(a.y);
        f[2] = (short)f2bf(a.z); f[3] = (short)f2bf(a.w);
        f[4] = (short)f2bf(b.x); f[5] = (short)f2bf(b.y);
        f[6] = (short)f2bf(b.z); f[7] = (short)f2bf(b.w);
        *(bf16x8*)(xf + (size_t)e * 8) = f;
    }
    __syncthreads();

    // per-lane top-2 (value, code) per nt-row
    float b0[4], b1[4]; int c0[4], c1[4];
    #pragma unroll
    for (int nt = 0; nt < 4; ++nt) { b0[nt] = 1e30f; b1[nt] = 1e30f; c0[nt] = 0; c1[nt] = 0; }

    const u16* ap0 = ch + (size_t)((m_w * 2 + 0) * 16 + l15) * D + l4 * 8;
    const u16* ap1 = ch + (size_t)((m_w * 2 + 1) * 16 + l15) * D + l4 * 8;
    // LDS read base for this wave's n-slice: entries ((n_w*4+nt)*8 + c)*64 + lane
    const u16* xfb = xf + (size_t)(n_w * 4 * 8 * 64 + lane) * 8;

    #pragma unroll 1
    for (int ct = 0; ct < 64; ++ct) {
        const int k0 = ct << 7;
        // A fragments: 16 direct 16B loads from L2-resident bf16 codebook.
        bf16x8 Af0[8], Af1[8];
        {
            const u16* a0 = ap0 + (size_t)k0 * D;
            const u16* a1 = ap1 + (size_t)k0 * D;
            #pragma unroll
            for (int c = 0; c < 8; ++c) {
                Af0[c] = *(const bf16x8*)(a0 + c * 32);
                Af1[c] = *(const bf16x8*)(a1 + c * 32);
            }
        }

        f32x4 acc[2][4];
        #pragma unroll
        for (int mt = 0; mt < 2; ++mt)
            #pragma unroll
            for (int nt = 0; nt < 4; ++nt) acc[mt][nt] = (f32x4){0.f, 0.f, 0.f, 0.f};

        #pragma unroll
        for (int c = 0; c < 8; ++c) {
            #pragma unroll
            for (int nt = 0; nt < 4; ++nt) {
                bf16x8 Bv = *(const bf16x8*)(xfb + (size_t)((nt * 8 + c) * 64) * 8);
                acc[0][nt] = __builtin_amdgcn_mfma_f32_16x16x32_bf16(Af0[c], Bv, acc[0][nt], 0, 0, 0);
                acc[1][nt] = __builtin_amdgcn_mfma_f32_16x16x32_bf16(Af1[c], Bv, acc[1][nt], 0, 0, 0);
            }
        }

        // epilogue: t = se - 2*dot ; per-lane top-2 (recompute t in rare path)
        f32x4 sev[2];
        #pragma unroll
        for (int mt = 0; mt < 2; ++mt)
            sev[mt] = *(const f32x4*)(se + k0 + (m_w * 2 + mt) * 16 + l4 * 4);

        #pragma unroll
        for (int nt = 0; nt < 4; ++nt) {
            float tmn = 1e30f;
            #pragma unroll
            for (int mt = 0; mt < 2; ++mt)
                #pragma unroll
                for (int r = 0; r < 4; ++r)
                    tmn = fminf(tmn, fmaf(-2.f, acc[mt][nt][r], sev[mt][r]));
            if (tmn < b1[nt]) {                    // rare after first tiles
                #pragma unroll
                for (int mt = 0; mt < 2; ++mt)
                    #pragma unroll
                    for (int r = 0; r < 4; ++r) {
                        float t = fmaf(-2.f, acc[mt][nt][r], sev[mt][r]);
                        int  cv = k0 + (m_w * 2 + mt) * 16 + l4 * 4 + r;
                        bool in0 = t < b0[nt];
                        bool in1 = t < b1[nt];
                        float ob0 = b0[nt]; int oc0 = c0[nt];
                        b1[nt] = in0 ? ob0 : (in1 ? t  : b1[nt]);
                        c1[nt] = in0 ? oc0 : (in1 ? cv : c1[nt]);
                        b0[nt] = in0 ? t  : ob0;
                        c0[nt] = in0 ? cv : oc0;
                    }
            }
        }
    }

    // ---- fixed-slot handoff (no atomics) ----
    #pragma unroll
    for (int nt = 0; nt < 4; ++nt) {
        int rl = n_w * 64 + nt * 16 + l15;
        int sl = (m_w * 4 + l4) * 2;
        cand[rl][sl]     = (u32)c0[nt];
        cand[rl][sl + 1] = (u32)c1[nt];
    }

    // ---- exact fp32 rescore of all 32 slots (round-1 arithmetic) ----
    const int rr = tid >> 2;       // 0..127
    const int cq = tid & 3;
    const int grow = row0 + rr;
    {
        const float* p = x + (size_t)grow * D + cq * 64;
        float sp = 0.f;
        #pragma unroll 8
        for (int j = 0; j < 64; ++j) { float v = p[j]; sp += v * v; }
        red_sx[rr][cq] = sp;
    }
    __syncthreads();   // cand + red_sx visible
    float sx = ((red_sx[rr][0] + red_sx[rr][1]) + red_sx[rr][2]) + red_sx[rr][3];

    float best = 1e30f; int bk = 0x7fffffff;
    const float* xr = x + (size_t)grow * D;
    for (int j = cq; j < 32; j += 4) {
        int code = (int)cand[rr][j];
        const float* er = cb + (size_t)code * D;
        float a = 0.f;
        #pragma unroll 8
        for (int d2 = 0; d2 < D; ++d2) a = fmaf(xr[d2], er[d2], a);
        float dist = (sx + se[code]) - 2.0f * a;
        if (dist < best || (dist == best && code < bk)) { best = dist; bk = code; }
    }
    red_bv[rr][cq] = best; red_bk[rr][cq] = bk;
    __syncthreads();
    if (cq == 0) {
        float bv = red_bv[rr][0]; int b = red_bk[rr][0];
        #pragma unroll
        for (int t2 = 1; t2 < 4; ++t2) {
            float v = red_bv[rr][t2]; int k2 = red_bk[rr][t2];
            if (v < bv || (v == bv && k2 < b)) { bv = v; b = k2; }
        }
        out_idx[grow] = b;
        out_f[QELEMS + grow] = (float)b;   // idx-as-float (disjoint from ch region)
    }
}

// ---------------------------------------------------------------------------
// Gather quantized + loss partial. 2048 blocks, 16 rows each, ONE atomic/block.
__global__ __launch_bounds__(256) void vq_out_kernel(
    const float* __restrict__ x, const float* __restrict__ cb,
    const int* __restrict__ idx, float* __restrict__ out,
    float* __restrict__ loss_sum) {

    float s = 0.f;
    #pragma unroll
    for (int i = 0; i < 4; ++i) {
        int g = blockIdx.x * 1024 + i * 256 + threadIdx.x;
        int row = g >> 6;
        int seg = (g & 63) * 4;
        int k = idx[row];
        float4 q  = *(const float4*)(cb + (size_t)k * D + seg);
        float4 xv = *(const float4*)(x + (size_t)row * D + seg);
        *(float4*)(out + (size_t)row * D + seg) = q;
        float dx0 = q.x - xv.x, dx1 = q.y - xv.y, dx2 = q.z - xv.z, dx3 = q.w - xv.w;
        s += dx0 * dx0 + dx1 * dx1 + dx2 * dx2 + dx3 * dx3;
    }

    __shared__ float red[256];
    red[threadIdx.x] = s;
    __syncthreads();
    #pragma unroll
    for (int off = 128; off > 0; off >>= 1) {
        if (threadIdx.x < off) red[threadIdx.x] += red[threadIdx.x + off];
        __syncthreads();
    }
    if (threadIdx.x == 0) atomicAdd(loss_sum, red[0]);
}

// ---------------------------------------------------------------------------
__global__ void vq_fin_kernel(const float* __restrict__ loss_sum, float* __restrict__ out) {
    out[QELEMS + NROWS] = 1.25f * (*loss_sum) * (1.0f / (float)QELEMS);
}

// ---------------------------------------------------------------------------
extern "C" void kernel_launch(void* const* d_in, const int* in_sizes, int n_in,
                              void* d_out, int out_size, void* d_ws, size_t ws_size,
                              hipStream_t stream) {
    const float* x  = (const float*)d_in[0];   // [16,2048,256] fp32
    const float* cb = (const float*)d_in[1];   // [8192,256] fp32
    float* out = (float*)d_out;

    // bf16 codebook scratch in d_out bytes [0, 4.19M) — consumed by vq_mfma
    // before vq_out overwrites the quantized region.
    u16* ch = (u16*)d_out;

    char* ws = (char*)d_ws;
    float* loss_sum = (float*)ws;                       // 4 B
    int*   idxbuf   = (int*)(ws + 256);                 // 128 KB
    float* sebuf    = (float*)(ws + 256 + NROWS * 4);   // 32 KB

    vq_prep_kernel<<<K / 4, 256, 0, stream>>>(cb, ch, sebuf, loss_sum);
    vq_mfma_kernel<<<NROWS / 128, 512, 0, stream>>>(ch, x, cb, sebuf, idxbuf, out);
    vq_out_kernel<<<NROWS / 16, 256, 0, stream>>>(x, cb, idxbuf, out, loss_sum);
    vq_fin_kernel<<<1, 1, 0, stream>>>(loss_sum, out);
}

// Round 7
// 456.063 us; speedup vs baseline: 4.6317x; 1.2530x over previous
//
#include <hip/hip_runtime.h>
#include <hip/hip_bf16.h>
#include <stdint.h>

#define D      256
#define K      8192
#define NROWS  32768          // 16 * 2048
#define QELEMS 8388608        // NROWS * D
// d_out layout (flat f32): [0,QELEMS) quantized, [QELEMS,QELEMS+NROWS) idx, [QELEMS+NROWS] loss

typedef __attribute__((ext_vector_type(8))) short bf16x8;
typedef __attribute__((ext_vector_type(4))) float f32x4;
typedef unsigned int u32;
typedef unsigned short u16;

__device__ __forceinline__ u16 f2bf(float f) {
    u32 b = __float_as_uint(f);
    return (u16)((b + 0x7fffu + ((b >> 16) & 1u)) >> 16);   // RNE
}

// ---------------------------------------------------------------------------
// Prep: cb fp32 -> ch bf16, se[k] = ||cb[k]||^2, zero loss accumulator.
__global__ __launch_bounds__(256) void vq_prep_kernel(
    const float* __restrict__ cb, u16* __restrict__ ch,
    float* __restrict__ se, float* __restrict__ loss_sum) {
    int row = blockIdx.x * 4 + (threadIdx.x >> 6);
    int l = threadIdx.x & 63;
    float4 v = *(const float4*)(cb + (size_t)row * D + l * 4);
    ushort4 o;
    o.x = f2bf(v.x); o.y = f2bf(v.y); o.z = f2bf(v.z); o.w = f2bf(v.w);
    *(ushort4*)(ch + (size_t)row * D + l * 4) = o;
    float s = v.x * v.x + v.y * v.y + v.z * v.z + v.w * v.w;
    #pragma unroll
    for (int off = 32; off > 0; off >>= 1) s += __shfl_down(s, off, 64);
    if (l == 0) se[row] = s;
    if (blockIdx.x == 0 && threadIdx.x == 0) *loss_sum = 0.f;
}

// ---------------------------------------------------------------------------
// Filter: bf16 MFMA distance scan. A-tile (128 codes x 256 d) staged in LDS
// via async global_load_lds (m97 pattern, 2 barriers/tile); x-frags in LDS
// (staged once); per-lane top-2 -> 32 candidate slots per row in global ws.
// Codes = MFMA M dim, rows = N dim.
__global__ __launch_bounds__(512) void vq_filter_kernel(
    const u16* __restrict__ ch, const float* __restrict__ x,
    const float* __restrict__ se, u32* __restrict__ cand)
{
    __shared__ u16 xf[32768];          // 64 KB: 128 rows x 256 d bf16, frag order
    __shared__ u16 As[32768];          // 64 KB: 128 codes x 256 d bf16, frag order

    const int tid  = threadIdx.x;
    const int lane = tid & 63;
    const int wave = tid >> 6;         // 0..7
    const int m_w  = wave >> 1;        // 0..3 : 32-code slice of 128-code tile
    const int n_w  = wave & 1;         // 0..1 : 64-row slice of 128-row block
    const int l15  = lane & 15;
    const int l4   = lane >> 4;        // 0..3
    const int row0 = blockIdx.x * 128;

    // ---- one-time stage: x (fp32, global) -> xf (bf16, LDS) in frag order ----
    #pragma unroll
    for (int i = 0; i < 8; ++i) {
        int e  = tid + i * 512;
        int q  = e >> 6, le = e & 63;
        int rl = (q >> 3) * 16 + (le & 15);
        int kk = (q & 7) * 32 + (le >> 4) * 8;
        const float* xp = x + (size_t)(row0 + rl) * D + kk;
        float4 a = *(const float4*)xp;
        float4 b = *(const float4*)(xp + 4);
        bf16x8 f;
        f[0] = (short)f2bf(a.x); f[1] = (short)f2bf(a.y);
        f[2] = (short)f2bf(a.z); f[3] = (short)f2bf(a.w);
        f[4] = (short)f2bf(b.x); f[5] = (short)f2bf(b.y);
        f[6] = (short)f2bf(b.z); f[7] = (short)f2bf(b.w);
        *(bf16x8*)(xf + (size_t)e * 8) = f;
    }

    // per-lane top-2 (value, code) per nt-row
    float b0[4], b1[4]; int c0[4], c1[4];
    #pragma unroll
    for (int nt = 0; nt < 4; ++nt) { b0[nt] = 1e30f; b1[nt] = 1e30f; c0[nt] = 0; c1[nt] = 0; }

    // LDS read base for this wave's n-slice
    const u16* xfb = xf + (size_t)(n_w * 4 * 8 * 64 + lane) * 8;

    #pragma unroll 1
    for (int ct = 0; ct < 64; ++ct) {
        const int k0 = ct << 7;

        __syncthreads();   // all waves done reading As from previous tile
        // Stage A-tile: 64 chunks of (16 codes x 32 d); 8 async instrs/wave.
        // LDS dest base is wave-uniform; HW scatters lane*16B (frag order).
        #pragma unroll
        for (int i = 0; i < 8; ++i) {
            int g  = wave * 8 + i;             // 0..63
            int c  = g >> 3;                   // d-chunk 0..7
            int mg = g & 7;                    // 16-code group
            const u16* gp = ch + (size_t)(k0 + mg * 16 + l15) * D + c * 32 + l4 * 8;
            u16* lb = As + (size_t)((c * 8 + mg) * 64) * 8;   // wave-uniform
            __builtin_amdgcn_global_load_lds(
                (const __attribute__((address_space(1))) u32*)gp,
                (__attribute__((address_space(3))) u32*)lb, 16, 0, 0);
        }
        __syncthreads();   // staging drained (compiler emits vmcnt(0)) + visible

        f32x4 acc[2][4];
        #pragma unroll
        for (int mt = 0; mt < 2; ++mt)
            #pragma unroll
            for (int nt = 0; nt < 4; ++nt) acc[mt][nt] = (f32x4){0.f, 0.f, 0.f, 0.f};

        #pragma unroll
        for (int c = 0; c < 8; ++c) {
            bf16x8 Af0 = *(const bf16x8*)(As + (size_t)((c * 8 + m_w * 2 + 0) * 64 + lane) * 8);
            bf16x8 Af1 = *(const bf16x8*)(As + (size_t)((c * 8 + m_w * 2 + 1) * 64 + lane) * 8);
            #pragma unroll
            for (int nt = 0; nt < 4; ++nt) {
                bf16x8 Bv = *(const bf16x8*)(xfb + (size_t)((nt * 8 + c) * 64) * 8);
                acc[0][nt] = __builtin_amdgcn_mfma_f32_16x16x32_bf16(Af0, Bv, acc[0][nt], 0, 0, 0);
                acc[1][nt] = __builtin_amdgcn_mfma_f32_16x16x32_bf16(Af1, Bv, acc[1][nt], 0, 0, 0);
            }
        }

        // epilogue: t = se - 2*dot ; per-lane top-2 (identical to R3-R6)
        f32x4 sev[2];
        #pragma unroll
        for (int mt = 0; mt < 2; ++mt)
            sev[mt] = *(const f32x4*)(se + k0 + (m_w * 2 + mt) * 16 + l4 * 4);

        #pragma unroll
        for (int nt = 0; nt < 4; ++nt) {
            float tmn = 1e30f;
            #pragma unroll
            for (int mt = 0; mt < 2; ++mt)
                #pragma unroll
                for (int r = 0; r < 4; ++r)
                    tmn = fminf(tmn, fmaf(-2.f, acc[mt][nt][r], sev[mt][r]));
            if (tmn < b1[nt]) {                    // rare after first tiles
                #pragma unroll
                for (int mt = 0; mt < 2; ++mt)
                    #pragma unroll
                    for (int r = 0; r < 4; ++r) {
                        float t = fmaf(-2.f, acc[mt][nt][r], sev[mt][r]);
                        int  cv = k0 + (m_w * 2 + mt) * 16 + l4 * 4 + r;
                        bool in0 = t < b0[nt];
                        bool in1 = t < b1[nt];
                        float ob0 = b0[nt]; int oc0 = c0[nt];
                        b1[nt] = in0 ? ob0 : (in1 ? t  : b1[nt]);
                        c1[nt] = in0 ? oc0 : (in1 ? cv : c1[nt]);
                        b0[nt] = in0 ? t  : ob0;
                        c0[nt] = in0 ? cv : oc0;
                    }
            }
        }
    }

    // ---- write 32 fixed candidate slots per row to global ws ----
    #pragma unroll
    for (int nt = 0; nt < 4; ++nt) {
        int row = row0 + n_w * 64 + nt * 16 + l15;
        int sl  = (m_w * 4 + l4) * 2;
        cand[(size_t)row * 32 + sl]     = (u32)c0[nt];
        cand[(size_t)row * 32 + sl + 1] = (u32)c1[nt];
    }
}

// ---------------------------------------------------------------------------
// Rescore + output: one wave per row. Coalesced float4 dots over the 32
// candidates (butterfly reduce), pick fp32 argmin, write quantized + idx +
// block-reduced loss partial (one atomic per block).
__global__ __launch_bounds__(1024) void vq_rescore_kernel(
    const float* __restrict__ x, const float* __restrict__ cb,
    const float* __restrict__ se, const u32* __restrict__ cand,
    float* __restrict__ out, float* __restrict__ loss_sum)
{
    const int wave = threadIdx.x >> 6;
    const int lane = threadIdx.x & 63;
    const int row  = blockIdx.x * 16 + wave;

    float4 xv = *(const float4*)(x + (size_t)row * D + lane * 4);
    float sx = xv.x * xv.x + xv.y * xv.y + xv.z * xv.z + xv.w * xv.w;
    #pragma unroll
    for (int o = 1; o < 64; o <<= 1) sx += __shfl_xor(sx, o, 64);

    u32 myc = cand[(size_t)row * 32 + (lane & 31)];
    float best = 1e30f; int bk = 0x7fffffff;
    #pragma unroll 4
    for (int j = 0; j < 32; ++j) {
        int code = __shfl((int)myc, j, 64);
        float4 ev = *(const float4*)(cb + (size_t)code * D + lane * 4);
        float p = xv.x * ev.x + xv.y * ev.y + xv.z * ev.z + xv.w * ev.w;
        #pragma unroll
        for (int o = 1; o < 64; o <<= 1) p += __shfl_xor(p, o, 64);
        float dist = (sx + se[code]) - 2.0f * p;
        if (dist < best || (dist == best && code < bk)) { best = dist; bk = code; }
    }

    float4 q = *(const float4*)(cb + (size_t)bk * D + lane * 4);
    *(float4*)(out + (size_t)row * D + lane * 4) = q;
    float dx = q.x - xv.x, dy = q.y - xv.y, dz = q.z - xv.z, dw = q.w - xv.w;
    float s = dx * dx + dy * dy + dz * dz + dw * dw;
    #pragma unroll
    for (int o = 1; o < 64; o <<= 1) s += __shfl_xor(s, o, 64);
    if (lane == 0) out[QELEMS + row] = (float)bk;

    __shared__ float red[16];
    if (lane == 0) red[wave] = s;
    __syncthreads();
    if (threadIdx.x == 0) {
        float t = 0.f;
        #pragma unroll
        for (int w2 = 0; w2 < 16; ++w2) t += red[w2];
        atomicAdd(loss_sum, t);
    }
}

// ---------------------------------------------------------------------------
__global__ void vq_fin_kernel(const float* __restrict__ loss_sum, float* __restrict__ out) {
    out[QELEMS + NROWS] = 1.25f * (*loss_sum) * (1.0f / (float)QELEMS);
}

// ---------------------------------------------------------------------------
extern "C" void kernel_launch(void* const* d_in, const int* in_sizes, int n_in,
                              void* d_out, int out_size, void* d_ws, size_t ws_size,
                              hipStream_t stream) {
    const float* x  = (const float*)d_in[0];   // [16,2048,256] fp32
    const float* cb = (const float*)d_in[1];   // [8192,256] fp32
    float* out = (float*)d_out;

    // bf16 codebook scratch in d_out bytes [0, 4 MiB) — dead before the
    // rescore kernel (which overwrites it with quantized rows 0..4095).
    u16* ch = (u16*)d_out;

    char* ws = (char*)d_ws;
    float* loss_sum = (float*)ws;               // @0, 4 B
    float* sebuf    = (float*)(ws + 4096);      // 32 KB
    u32*   cand     = (u32*)(ws + 65536);       // 32768*32*4 = 4 MiB

    vq_prep_kernel<<<K / 4, 256, 0, stream>>>(cb, ch, sebuf, loss_sum);
    vq_filter_kernel<<<NROWS / 128, 512, 0, stream>>>(ch, x, sebuf, cand);
    vq_rescore_kernel<<<NROWS / 16, 1024, 0, stream>>>(x, cb, sebuf, cand, out, loss_sum);
    vq_fin_kernel<<<1, 1, 0, stream>>>(loss_sum, out);
}

// Round 8
// 393.518 us; speedup vs baseline: 5.3679x; 1.1589x over previous
//
#include <hip/hip_runtime.h>
#include <hip/hip_bf16.h>
#include <stdint.h>

#define D      256
#define K      8192
#define NROWS  32768          // 16 * 2048
#define QELEMS 8388608        // NROWS * D
// d_out layout (flat f32): [0,QELEMS) quantized, [QELEMS,QELEMS+NROWS) idx, [QELEMS+NROWS] loss

typedef __attribute__((ext_vector_type(8))) short bf16x8;
typedef __attribute__((ext_vector_type(4))) float f32x4;
typedef unsigned int u32;
typedef unsigned short u16;

__device__ __forceinline__ u16 f2bf(float f) {
    u32 b = __float_as_uint(f);
    return (u16)((b + 0x7fffu + ((b >> 16) & 1u)) >> 16);   // RNE
}

// ---------------------------------------------------------------------------
// Prep: cb fp32 -> ch bf16, se[k] = ||cb[k]||^2, zero loss accumulator.
__global__ __launch_bounds__(256) void vq_prep_kernel(
    const float* __restrict__ cb, u16* __restrict__ ch,
    float* __restrict__ se, float* __restrict__ loss_sum) {
    int row = blockIdx.x * 4 + (threadIdx.x >> 6);
    int l = threadIdx.x & 63;
    float4 v = *(const float4*)(cb + (size_t)row * D + l * 4);
    ushort4 o;
    o.x = f2bf(v.x); o.y = f2bf(v.y); o.z = f2bf(v.z); o.w = f2bf(v.w);
    *(ushort4*)(ch + (size_t)row * D + l * 4) = o;
    float s = v.x * v.x + v.y * v.y + v.z * v.z + v.w * v.w;
    #pragma unroll
    for (int off = 32; off > 0; off >>= 1) s += __shfl_down(s, off, 64);
    if (l == 0) se[row] = s;
    if (blockIdx.x == 0 && threadIdx.x == 0) *loss_sum = 0.f;
}

// ---------------------------------------------------------------------------
// Filter: bf16 MFMA scan. x-fragments (B operand) live in registers (64 VGPR,
// 32 rows/wave); A-tile (64 codes x 256 d, 32 KB) double-buffered in LDS via
// async global_load_lds, ONE barrier per tile (prefetch t+1 overlaps compute
// of t). Per c-iter: 2 ds_read_b128 + 4 MFMA. Block = 256 thr (2 m_w x 2 n_w),
// 64 rows/block, grid 512, 2 blocks/CU. Per-lane top-2 over 8 streams/row ->
// 16 candidate slots/row.
__global__ __launch_bounds__(256) void vq_filter_kernel(
    const u16* __restrict__ ch, const float* __restrict__ x,
    const float* __restrict__ se, u32* __restrict__ cand)
{
    __shared__ u16 As[2][16384];       // 2 x 32 KB: 64 codes x 256 d, frag order

    const int tid  = threadIdx.x;
    const int lane = tid & 63;
    const int wave = tid >> 6;         // 0..3
    const int m_w  = wave & 1;         // 0..1 : 32-code slice of 64-code tile
    const int n_w  = wave >> 1;        // 0..1 : 32-row slice of 64-row block
    const int l15  = lane & 15;
    const int l4   = lane >> 4;        // 0..3
    const int row0 = blockIdx.x * 64;

    // ---- B operand: 32 rows x 256 d in registers, f2bf in-register ----
    bf16x8 Bf[2][8];                   // 64 VGPRs
    #pragma unroll
    for (int nt = 0; nt < 2; ++nt) {
        const float* xr = x + (size_t)(row0 + n_w * 32 + nt * 16 + l15) * D + l4 * 8;
        #pragma unroll
        for (int c = 0; c < 8; ++c) {
            float4 a = *(const float4*)(xr + c * 32);
            float4 b = *(const float4*)(xr + c * 32 + 4);
            bf16x8 f;
            f[0] = (short)f2bf(a.x); f[1] = (short)f2bf(a.y);
            f[2] = (short)f2bf(a.z); f[3] = (short)f2bf(a.w);
            f[4] = (short)f2bf(b.x); f[5] = (short)f2bf(b.y);
            f[6] = (short)f2bf(b.z); f[7] = (short)f2bf(b.w);
            Bf[nt][c] = f;
        }
    }

    // per-lane top-2 (value, code) per nt-row
    float b0[2], b1[2]; int c0[2], c1[2];
    #pragma unroll
    for (int nt = 0; nt < 2; ++nt) { b0[nt] = 1e30f; b1[nt] = 1e30f; c0[nt] = 0; c1[nt] = 0; }

    // ---- prologue: stage tile 0 into buffer 0 (8 async instrs/wave) ----
    // chunk g in [0,32): code-group mg=g&3 (16 codes), d-chunk c=g>>2 (32 d).
    #pragma unroll
    for (int i = 0; i < 8; ++i) {
        int g = wave * 8 + i;
        const u16* gp = ch + (size_t)((g & 3) * 16 + l15) * D + (g >> 2) * 32 + l4 * 8;
        u16* lb = &As[0][(size_t)g * 512];          // wave-uniform; HW adds lane*16B
        __builtin_amdgcn_global_load_lds(
            (const __attribute__((address_space(1))) u32*)gp,
            (__attribute__((address_space(3))) u32*)lb, 16, 0, 0);
    }
    __syncthreads();

    int buf = 0;
    #pragma unroll 1
    for (int ct = 0; ct < 128; ++ct) {
        const int k0 = ct << 6;

        // prefetch tile ct+1 into As[buf^1] (overlaps compute below)
        if (ct + 1 < 128) {
            const int kn = (ct + 1) << 6;
            #pragma unroll
            for (int i = 0; i < 8; ++i) {
                int g = wave * 8 + i;
                const u16* gp = ch + (size_t)(kn + (g & 3) * 16 + l15) * D + (g >> 2) * 32 + l4 * 8;
                u16* lb = &As[buf ^ 1][(size_t)g * 512];
                __builtin_amdgcn_global_load_lds(
                    (const __attribute__((address_space(1))) u32*)gp,
                    (__attribute__((address_space(3))) u32*)lb, 16, 0, 0);
            }
        }

        // compute tile ct from As[buf]
        const u16* cb_t = &As[buf][0];
        f32x4 acc[2][2];
        #pragma unroll
        for (int mt = 0; mt < 2; ++mt)
            #pragma unroll
            for (int nt = 0; nt < 2; ++nt) acc[mt][nt] = (f32x4){0.f, 0.f, 0.f, 0.f};

        #pragma unroll
        for (int c = 0; c < 8; ++c) {
            bf16x8 Af0 = *(const bf16x8*)(cb_t + (size_t)((c * 4 + m_w * 2 + 0) * 64 + lane) * 8);
            bf16x8 Af1 = *(const bf16x8*)(cb_t + (size_t)((c * 4 + m_w * 2 + 1) * 64 + lane) * 8);
            acc[0][0] = __builtin_amdgcn_mfma_f32_16x16x32_bf16(Af0, Bf[0][c], acc[0][0], 0, 0, 0);
            acc[0][1] = __builtin_amdgcn_mfma_f32_16x16x32_bf16(Af0, Bf[1][c], acc[0][1], 0, 0, 0);
            acc[1][0] = __builtin_amdgcn_mfma_f32_16x16x32_bf16(Af1, Bf[0][c], acc[1][0], 0, 0, 0);
            acc[1][1] = __builtin_amdgcn_mfma_f32_16x16x32_bf16(Af1, Bf[1][c], acc[1][1], 0, 0, 0);
        }

        // epilogue: t = se - 2*dot ; per-lane top-2 (same arithmetic as R3-R7)
        f32x4 sev[2];
        #pragma unroll
        for (int mt = 0; mt < 2; ++mt)
            sev[mt] = *(const f32x4*)(se + k0 + (m_w * 2 + mt) * 16 + l4 * 4);

        #pragma unroll
        for (int nt = 0; nt < 2; ++nt) {
            float tmn = 1e30f;
            #pragma unroll
            for (int mt = 0; mt < 2; ++mt)
                #pragma unroll
                for (int r = 0; r < 4; ++r)
                    tmn = fminf(tmn, fmaf(-2.f, acc[mt][nt][r], sev[mt][r]));
            if (tmn < b1[nt]) {
                #pragma unroll
                for (int mt = 0; mt < 2; ++mt)
                    #pragma unroll
                    for (int r = 0; r < 4; ++r) {
                        float t = fmaf(-2.f, acc[mt][nt][r], sev[mt][r]);
                        int  cv = k0 + (m_w * 2 + mt) * 16 + l4 * 4 + r;
                        bool in0 = t < b0[nt];
                        bool in1 = t < b1[nt];
                        float ob0 = b0[nt]; int oc0 = c0[nt];
                        b1[nt] = in0 ? ob0 : (in1 ? t  : b1[nt]);
                        c1[nt] = in0 ? oc0 : (in1 ? cv : c1[nt]);
                        b0[nt] = in0 ? t  : ob0;
                        c0[nt] = in0 ? cv : oc0;
                    }
            }
        }

        __syncthreads();   // drain prefetch (vmcnt) + all waves done with As[buf]
        buf ^= 1;
    }

    // ---- write 16 fixed candidate slots per row to global ws ----
    #pragma unroll
    for (int nt = 0; nt < 2; ++nt) {
        int row = row0 + n_w * 32 + nt * 16 + l15;
        int sl  = (m_w * 4 + l4) * 2;
        cand[(size_t)row * 16 + sl]     = (u32)c0[nt];
        cand[(size_t)row * 16 + sl + 1] = (u32)c1[nt];
    }
}

// ---------------------------------------------------------------------------
// Rescore + output: one wave per row. Coalesced float4 dots over the 16
// candidates (butterfly reduce), fp32 argmin (round-1 formula), write
// quantized + idx + block-reduced loss partial (one atomic per block).
__global__ __launch_bounds__(1024) void vq_rescore_kernel(
    const float* __restrict__ x, const float* __restrict__ cb,
    const float* __restrict__ se, const u32* __restrict__ cand,
    float* __restrict__ out, float* __restrict__ loss_sum)
{
    const int wave = threadIdx.x >> 6;
    const int lane = threadIdx.x & 63;
    const int row  = blockIdx.x * 16 + wave;

    float4 xv = *(const float4*)(x + (size_t)row * D + lane * 4);
    float sx = xv.x * xv.x + xv.y * xv.y + xv.z * xv.z + xv.w * xv.w;
    #pragma unroll
    for (int o = 1; o < 64; o <<= 1) sx += __shfl_xor(sx, o, 64);

    u32 myc = cand[(size_t)row * 16 + (lane & 15)];
    float best = 1e30f; int bk = 0x7fffffff;
    #pragma unroll 4
    for (int j = 0; j < 16; ++j) {
        int code = __shfl((int)myc, j, 64);
        float4 ev = *(const float4*)(cb + (size_t)code * D + lane * 4);
        float p = xv.x * ev.x + xv.y * ev.y + xv.z * ev.z + xv.w * ev.w;
        #pragma unroll
        for (int o = 1; o < 64; o <<= 1) p += __shfl_xor(p, o, 64);
        float dist = (sx + se[code]) - 2.0f * p;
        if (dist < best || (dist == best && code < bk)) { best = dist; bk = code; }
    }

    float4 q = *(const float4*)(cb + (size_t)bk * D + lane * 4);
    *(float4*)(out + (size_t)row * D + lane * 4) = q;
    float dx = q.x - xv.x, dy = q.y - xv.y, dz = q.z - xv.z, dw = q.w - xv.w;
    float s = dx * dx + dy * dy + dz * dz + dw * dw;
    #pragma unroll
    for (int o = 1; o < 64; o <<= 1) s += __shfl_xor(s, o, 64);
    if (lane == 0) out[QELEMS + row] = (float)bk;

    __shared__ float red[16];
    if (lane == 0) red[wave] = s;
    __syncthreads();
    if (threadIdx.x == 0) {
        float t = 0.f;
        #pragma unroll
        for (int w2 = 0; w2 < 16; ++w2) t += red[w2];
        atomicAdd(loss_sum, t);
    }
}

// ---------------------------------------------------------------------------
__global__ void vq_fin_kernel(const float* __restrict__ loss_sum, float* __restrict__ out) {
    out[QELEMS + NROWS] = 1.25f * (*loss_sum) * (1.0f / (float)QELEMS);
}

// ---------------------------------------------------------------------------
extern "C" void kernel_launch(void* const* d_in, const int* in_sizes, int n_in,
                              void* d_out, int out_size, void* d_ws, size_t ws_size,
                              hipStream_t stream) {
    const float* x  = (const float*)d_in[0];   // [16,2048,256] fp32
    const float* cb = (const float*)d_in[1];   // [8192,256] fp32
    float* out = (float*)d_out;

    // bf16 codebook scratch in d_out bytes [0, 4 MiB) — dead before the
    // rescore kernel (which overwrites it with quantized rows).
    u16* ch = (u16*)d_out;

    char* ws = (char*)d_ws;
    float* loss_sum = (float*)ws;               // @0, 4 B
    float* sebuf    = (float*)(ws + 4096);      // 32 KB
    u32*   cand     = (u32*)(ws + 65536);       // 32768*16*4 = 2 MiB

    vq_prep_kernel<<<K / 4, 256, 0, stream>>>(cb, ch, sebuf, loss_sum);
    vq_filter_kernel<<<NROWS / 64, 256, 0, stream>>>(ch, x, sebuf, cand);
    vq_rescore_kernel<<<NROWS / 16, 1024, 0, stream>>>(x, cb, sebuf, cand, out, loss_sum);
    vq_fin_kernel<<<1, 1, 0, stream>>>(loss_sum, out);
}